// Round 4
// baseline (129.581 us; speedup 1.0000x reference)
//
#include <hip/hip_runtime.h>

namespace {
constexpr int BATCH = 512;
constexpr int SEQL  = 512;
constexpr int HID   = 256;
constexpr int MORPH = 24;
constexpr float NEGV = -1.0e9f;
}

__device__ __forceinline__ unsigned okey(float f) {
    unsigned u = __float_as_uint(f);
    return u ^ (unsigned)(((int)u >> 31) | 0x80000000);
}

// ---- Kernel A: order-keys for all (b,l) + zero menc region.
// grid 4096: blk = (b<<3)|q, rows [64q, 64q+64). 256 thr = 4 waves, wave-per-row.
extern "C" __global__ __launch_bounds__(256)
void k_scores(const float* __restrict__ we, const int* __restrict__ wlen,
              const float* __restrict__ Wv, const float* __restrict__ bias,
              unsigned* __restrict__ keys, float* __restrict__ menc)
{
    const int blk = blockIdx.x;
    const int b = blk >> 3, q = blk & 7;
    const int tid = threadIdx.x, lane = tid & 63, wave = tid >> 6;
    const int wl = wlen[b];
    const float b0 = bias[0];
    const float* __restrict__ werow = we + (size_t)b * (SEQL * HID);
    const unsigned KEYNEG = okey(NEGV);

    // zero menc: 512*24*256 floats = 4096 blocks * 768 floats exactly
    {
        const float4 z = {0.f, 0.f, 0.f, 0.f};
        float4* mz = reinterpret_cast<float4*>(menc) + (size_t)blk * 192;
        if (tid < 192) mz[tid] = z;
    }

    const float4 w4 = reinterpret_cast<const float4*>(Wv)[lane];
    const int rs = q * 64;
    const int nvalid = wl - 1;
    for (int l = rs + wave; l < rs + 64; l += 4) {
        unsigned kk = KEYNEG;
        if (l < nvalid) {                       // wave-uniform
            const float4 v = reinterpret_cast<const float4*>(werow + (size_t)l * HID)[lane];
            float p = v.x * w4.x + v.y * w4.y + v.z * w4.z + v.w * w4.w;
            #pragma unroll
            for (int off = 32; off >= 1; off >>= 1)
                p += __shfl_xor(p, off, 64);
            kk = okey(p + b0);
        }
        if (lane == 0) keys[b * SEQL + l] = kk;
    }
}

// ---- Kernel B: radix-select top-(nm-1), c2m (->ws), bpm. grid 512 x 512 thr.
extern "C" __global__ __launch_bounds__(512)
void k_select(const unsigned* __restrict__ keys, const int* __restrict__ wlen,
              const int* __restrict__ nmorph, unsigned char* __restrict__ c2m_g,
              float* __restrict__ out)
{
    const int b = blockIdx.x;
    const int tid = threadIdx.x, lane = tid & 63, wave = tid >> 6;

    __shared__ unsigned s_keys[SEQL];
    __shared__ int s_hist[256];
    __shared__ int s_c2m[SEQL];
    __shared__ unsigned long long s_eqm[8], s_ind[8];
    __shared__ unsigned s_p, s_T;
    __shared__ int s_Kr, s_KrF, s_done;

    const int wl = wlen[b];
    const int nm = nmorph[b];
    const int K  = nm - 1;

    s_keys[tid] = keys[b * SEQL + tid];
    if (tid == 0) { s_p = 0u; s_Kr = K; s_done = 0; }
    __syncthreads();

    int done = 0;
    for (int pass = 0; pass < 4 && !done; ++pass) {
        const int shift = 24 - 8 * pass;
        if (tid < 256) s_hist[tid] = 0;
        __syncthreads();
        {
            const unsigned k = s_keys[tid];
            const bool act = (pass == 0) ||
                             ((k >> (shift + 8)) == (s_p >> (shift + 8)));
            if (act) atomicAdd(&s_hist[(k >> shift) & 255], 1);
        }
        __syncthreads();
        if (wave == 0) {
            const int v0 = lane * 4;
            const int h0 = s_hist[v0], h1 = s_hist[v0 + 1];
            const int h2 = s_hist[v0 + 2], h3 = s_hist[v0 + 3];
            const int local = h0 + h1 + h2 + h3;
            int T = local;
            #pragma unroll
            for (int off = 1; off < 64; off <<= 1) {
                const int u = __shfl_down(T, off, 64);
                if (lane + off < 64) T += u;
            }
            const int A  = T - local;
            const int S3 = A + h3, S2 = S3 + h2, S1 = S2 + h1, S0 = S1 + h0;
            const int Kr = s_Kr;
            const unsigned p = s_p;
            int v = -1, Sv = 0, Sv1 = 0;
            if (A  < Kr && Kr <= S3) { v = v0 + 3; Sv = S3; Sv1 = A;  }
            if (S3 < Kr && Kr <= S2) { v = v0 + 2; Sv = S2; Sv1 = S3; }
            if (S2 < Kr && Kr <= S1) { v = v0 + 1; Sv = S1; Sv1 = S2; }
            if (S1 < Kr && Kr <= S0) { v = v0 + 0; Sv = S0; Sv1 = S1; }
            if (v >= 0) {
                const unsigned pv = p | ((unsigned)v << shift);
                if (Sv == Kr)       { s_T = pv - 1u; s_KrF = 0;        s_done = 1; }
                else if (shift == 0){ s_T = pv;      s_KrF = Kr - Sv1; s_done = 1; }
                else                { s_p = pv;      s_Kr = Kr - Sv1; }
            }
        }
        __syncthreads();
        done = s_done;
    }

    const unsigned Tf = s_T;
    const int KrF = s_KrF;
    const unsigned k = s_keys[tid];
    const bool gt = (k > Tf);
    const bool eq = (k == Tf);
    const unsigned long long eb = __ballot(eq);
    if (lane == 0) s_eqm[wave] = eb;
    __syncthreads();
    int f;
    {
        const unsigned long long lowmask = (1ull << lane) - 1ull;
        int r = 0;
        #pragma unroll
        for (int qq = 0; qq < 8; ++qq) {
            const unsigned long long w = s_eqm[qq];
            r += (qq < wave) ? __popcll(w) : ((qq == wave) ? __popcll(w & lowmask) : 0);
        }
        f = gt || (eq && r < KrF);
    }
    const unsigned long long fb = __ballot(f);
    if (lane == 0) s_ind[wave] = fb;
    __syncthreads();
    {
        const unsigned long long lowmask = (1ull << lane) - 1ull;
        int cnt = 0;
        #pragma unroll
        for (int qq = 0; qq < 8; ++qq) {
            const unsigned long long w = s_ind[qq];
            cnt += (qq < wave) ? __popcll(w) : ((qq == wave) ? __popcll(w & lowmask) : 0);
        }
        s_c2m[tid] = cnt;
        c2m_g[b * SEQL + tid] = (unsigned char)cnt;
    }
    __syncthreads();

    // bpm one-hot, float4 (6 per l-row)
    float* __restrict__ bpm = out + (size_t)BATCH * MORPH * HID + (size_t)b * (SEQL * MORPH);
    for (int v = tid; v < SEQL * MORPH / 4; v += 512) {
        const int l  = v / 6;
        const int qv = v - l * 6;
        const int c  = s_c2m[l];
        const int mb = qv * 4;
        const bool valid = (l < wl);
        float4 o;
        o.x = (valid && c == mb + 0 && mb + 0 < nm) ? 1.0f : 0.0f;
        o.y = (valid && c == mb + 1 && mb + 1 < nm) ? 1.0f : 0.0f;
        o.z = (valid && c == mb + 2 && mb + 2 < nm) ? 1.0f : 0.0f;
        o.w = (valid && c == mb + 3 && mb + 3 < nm) ? 1.0f : 0.0f;
        reinterpret_cast<float4*>(bpm)[v] = o;
    }
}

// ---- Kernel C: menc segment sums per (b, 64-row chunk).
// Internal morphemes: plain store. Chunk-straddling: atomicAdd onto A's zeros.
extern "C" __global__ __launch_bounds__(256)
void k_menc(const float* __restrict__ we, const int* __restrict__ wlen,
            const unsigned char* __restrict__ c2m_g, float* __restrict__ menc)
{
    const int blk = blockIdx.x;
    const int b = blk >> 3, q = blk & 7;
    const int tid = threadIdx.x, lane = tid & 63, wave = tid >> 6;
    const int wl = wlen[b];
    const int rs = q * 64;
    if (rs >= wl) return;                      // block-uniform
    const int re = min(rs + 64, wl);

    __shared__ float s_acc[MORPH][HID];        // 24 KB
    __shared__ unsigned char s_cl[66];         // c2m rows rs-1 .. rs+64

    if (tid < 66) {
        const int row = rs - 1 + tid;
        s_cl[tid] = (row >= 0 && row < SEQL) ? c2m_g[b * SEQL + row] : (unsigned char)255;
    }
    {
        float* af = &s_acc[0][0];
        for (int i = tid; i < MORPH * HID; i += 256) af[i] = 0.0f;
    }
    __syncthreads();

    const int m_first = s_cl[1];               // c2m[rs]
    const int m_last  = s_cl[re - rs];         // c2m[re-1]

    // wave-contiguous sub-ranges of [rs, re)
    const int n  = re - rs;
    const int lw0 = rs + (wave * n) / 4;
    const int lw1 = rs + ((wave + 1) * n) / 4;
    const float* __restrict__ werow = we + (size_t)b * (SEQL * HID);

    float4 acc = {0.f, 0.f, 0.f, 0.f};
    int mcur = -1;
    for (int l = lw0; l < lw1; ++l) {
        const int mm = s_cl[l - rs + 1];       // wave-uniform
        if (mm != mcur) {
            if (mcur >= 0) {
                atomicAdd(&s_acc[mcur][lane * 4 + 0], acc.x);
                atomicAdd(&s_acc[mcur][lane * 4 + 1], acc.y);
                atomicAdd(&s_acc[mcur][lane * 4 + 2], acc.z);
                atomicAdd(&s_acc[mcur][lane * 4 + 3], acc.w);
                acc.x = acc.y = acc.z = acc.w = 0.f;
            }
            mcur = mm;
        }
        const float4 v = reinterpret_cast<const float4*>(werow + (size_t)l * HID)[lane];
        acc.x += v.x; acc.y += v.y; acc.z += v.z; acc.w += v.w;
    }
    if (mcur >= 0) {
        atomicAdd(&s_acc[mcur][lane * 4 + 0], acc.x);
        atomicAdd(&s_acc[mcur][lane * 4 + 1], acc.y);
        atomicAdd(&s_acc[mcur][lane * 4 + 2], acc.z);
        atomicAdd(&s_acc[mcur][lane * 4 + 3], acc.w);
    }
    __syncthreads();

    // shared-with-neighbor tests
    const bool sp = (q > 0) && ((int)s_cl[0] == m_first);      // c2m[rs-1]==c2m[rs]
    const bool sn = (re < wl) && ((int)s_cl[65] == m_last);    // c2m[rs+64]==c2m[re-1]

    float* __restrict__ mout = menc + (size_t)b * (MORPH * HID);
    for (int m = m_first; m <= m_last; ++m) {
        const float v = s_acc[m][tid];
        const bool shared = (m == m_first && sp) || (m == m_last && sn);
        if (shared) atomicAdd(&mout[m * HID + tid], v);
        else        mout[m * HID + tid] = v;
    }
}

extern "C" void kernel_launch(void* const* d_in, const int* in_sizes, int n_in,
                              void* d_out, int out_size, void* d_ws, size_t ws_size,
                              hipStream_t stream) {
    const float* we     = (const float*)d_in[0];
    const int*   wlen   = (const int*)d_in[1];
    const int*   nmorph = (const int*)d_in[2];
    const float* Wv     = (const float*)d_in[3];
    const float* bias   = (const float*)d_in[4];
    float* out = (float*)d_out;

    unsigned*      keys = (unsigned*)d_ws;                       // 1 MB
    unsigned char* c2m  = (unsigned char*)d_ws + (1u << 20);     // 256 KB

    k_scores<<<dim3(BATCH * 8), dim3(256), 0, stream>>>(we, wlen, Wv, bias, keys, out);
    k_select<<<dim3(BATCH), dim3(512), 0, stream>>>(keys, wlen, nmorph, c2m, out);
    k_menc  <<<dim3(BATCH * 8), dim3(256), 0, stream>>>(we, wlen, c2m, out);
}